// Round 4
// baseline (150.128 us; speedup 1.0000x reference)
//
#include <hip/hip_runtime.h>

#define TSIZE   151
#define SUPPORT 512
#define TARGET  65024
#define NCLS    64
#define NPAIR   (TARGET / 2)  // 32512 row-pairs for gather_sum
#define NQUAD   (TARGET / 4)  // 16256 row-quads for direct kernel

struct Accum {
    float hist_pos_sp[8][80];   // spread pos-histogram accumulators (slots 0..75)
    float A[80];                // C[idx+1]  (cdf of pos hist)
    float B[80];                // Hpos[idx+1]
    float sum_all[8];
    float sum_pos[8];
    float nll_sum[8];
    int   sup_cnt[NCLS];
    int   tgt_cnt[NCLS];
    int   cls_off[NCLS + 1];
    int   cls_col[SUPPORT];
    unsigned long long mask[NCLS * 8];   // per-class 512-bit support membership
};

__device__ __forceinline__ void lds_fadd(float* p, float v) {
    __hip_atomic_fetch_add(p, v, __ATOMIC_RELAXED, __HIP_MEMORY_SCOPE_WORKGROUP);
}

// ---------------------------------------------------------------- prep
__global__ void prep_kernel(const int* __restrict__ labels, Accum* ws) {
    __shared__ int sh_cnt[NCLS], sh_off[NCLS], cur[NCLS];
    const int t = threadIdx.x;
    if (t < NCLS) { sh_cnt[t] = 0; cur[t] = 0; }
    __syncthreads();
    const int c = labels[t];
    atomicAdd(&sh_cnt[c], 1);
    atomicOr(&ws->mask[c * 8 + (t >> 6)], 1ull << (t & 63));
    __syncthreads();
    if (t == 0) {
        int o = 0;
        for (int i = 0; i < NCLS; ++i) { sh_off[i] = o; ws->cls_off[i] = o; o += sh_cnt[i]; }
        ws->cls_off[NCLS] = o;
    }
    __syncthreads();
    if (t < NCLS) ws->sup_cnt[t] = sh_cnt[t];
    const int slot = atomicAdd(&cur[c], 1);
    ws->cls_col[sh_off[c] + slot] = t;
}

// ---------------------------------------------------------------- pos histogram
// 8 threads per target row gather the positive columns (~8/row avg).
__global__ __launch_bounds__(256) void pos_hist_kernel(const float* __restrict__ ip,
                                                       const int* __restrict__ labels,
                                                       Accum* __restrict__ ws) {
    __shared__ float hp[77][8];
    __shared__ int   colL[SUPPORT];
    __shared__ int   offL[NCLS + 1];
    const int tid = threadIdx.x;
    for (int i = tid; i < 77 * 8; i += 256) (&hp[0][0])[i] = 0.0f;
    for (int i = tid; i < SUPPORT; i += 256) colL[i] = ws->cls_col[i];
    if (tid <= NCLS) offL[tid] = ws->cls_off[tid];
    __syncthreads();

    const int row = (blockIdx.x * 256 + tid) >> 3;   // 32 rows per block
    const int sl  = tid & 7;
    {
        const int c    = labels[SUPPORT + row];
        const int base = offL[c];
        const int cnt  = offL[c + 1] - base;
        const float* rptr = ip + (size_t)row * SUPPORT;
        for (int j = sl; j < cnt; j += 8) {
            const float s  = rptr[colL[base + j]];
            const float u  = s * 75.0f;
            const float fl = floorf(u);
            const float fr = u - fl;
            int idx = (int)fl;
            idx = idx < 0 ? 0 : (idx > 74 ? 74 : idx);
            lds_fadd(&hp[idx][sl],     fr);
            lds_fadd(&hp[idx + 1][sl], 1.0f - fr);
        }
    }
    __syncthreads();
    if (tid < 76) {
        float s = 0.0f;
        #pragma unroll
        for (int r = 0; r < 8; ++r) s += hp[tid][r];
        if (s != 0.0f) unsafeAtomicAdd(&ws->hist_pos_sp[blockIdx.x & 7][tid], s);
    }
}

// ---------------------------------------------------------------- cdf build
__global__ void cdf_kernel(Accum* ws) {
    __shared__ float H[80];
    const int t = threadIdx.x;
    if (t < 76) {
        float s = 0.0f;
        #pragma unroll
        for (int r = 0; r < 8; ++r) s += ws->hist_pos_sp[r][t];
        H[t] = s;
    }
    if (t >= 76 && t < 80) H[t] = 0.0f;
    __syncthreads();
    if (t == 0) {
        float c = 0.0f;
        float C[77];
        for (int i = 0; i < 76; ++i) { c += H[i]; C[i] = c; }
        for (int idx = 0; idx < 75; ++idx) { ws->A[idx] = C[idx + 1]; ws->B[idx] = H[idx + 1]; }
        ws->A[75] = C[75]; ws->B[75] = 0.0f;
        ws->A[76] = 0.0f;  ws->B[76] = 0.0f;
        ws->A[77] = 0.0f;  ws->B[77] = 0.0f;
        ws->A[78] = 0.0f;  ws->B[78] = 0.0f;
        ws->A[79] = 0.0f;  ws->B[79] = 0.0f;
    }
}

// ---------------------------------------------------------------- main pass
// Stream all 33.3M elements once; per element: ONE conflict-light ds_read_b64
// from a 32-way replicated (A,B) table + FMA into register sums.
__global__ __launch_bounds__(256) void gather_sum_kernel(const float* __restrict__ ip,
                                                         const int* __restrict__ labels,
                                                         Accum* __restrict__ ws) {
    __shared__ float2 tab[76 * 32];    // tab[idx*32 + (lane&31)] = (A[idx], B[idx])
    __shared__ float red[8];
    const int tid = threadIdx.x;
    const int c   = tid & 31;
    for (int i = tid; i < 76 * 32; i += 256) {
        const int idx = i >> 5;
        tab[i] = make_float2(ws->A[idx], ws->B[idx]);
    }
    __syncthreads();

    const int half = tid >> 7;            // which row of the pair
    const int word = (tid & 127) >> 4;    // u64 word of the 512-bit mask
    const int bit0 = (tid << 2) & 63;     // bit of first of the 4 columns

    float s_all = 0.0f, s_pos = 0.0f;
    int rp = blockIdx.x;
    float4 v; unsigned long long mw = 0;
    if (rp < NPAIR) {
        v = reinterpret_cast<const float4*>(ip)[rp * 256 + tid];
        const int lab = labels[SUPPORT + rp * 2 + half];
        mw = ws->mask[lab * 8 + word];
    }
    while (rp < NPAIR) {
        const int rpn = rp + gridDim.x;
        float4 vn; unsigned long long mwn = 0;
        if (rpn < NPAIR) {
            vn = reinterpret_cast<const float4*>(ip)[rpn * 256 + tid];
            const int labn = labels[SUPPORT + rpn * 2 + half];
            mwn = ws->mask[labn * 8 + word];
        }
        const unsigned nib = (unsigned)(mw >> bit0) & 0xFu;
        #pragma unroll
        for (int e = 0; e < 4; ++e) {
            const float s  = e == 0 ? v.x : e == 1 ? v.y : e == 2 ? v.z : v.w;
            const float u  = s * 75.0f;
            const float fl = floorf(u);
            const float fr = u - fl;
            int idx = (int)fl;
            idx = idx < 0 ? 0 : (idx > 74 ? 74 : idx);
            const float2 ab = tab[(idx << 5) + c];
            const float g = fmaf(-fr, ab.y, ab.x);   // C[idx+1] - fr*H[idx+1]
            s_all += g;
            if (nib & (1u << e)) s_pos += g;
        }
        v = vn; mw = mwn; rp = rpn;
    }

    #pragma unroll
    for (int off = 1; off < 64; off <<= 1) {
        s_all += __shfl_xor(s_all, off);
        s_pos += __shfl_xor(s_pos, off);
    }
    if ((tid & 63) == 0) { red[tid >> 6] = s_all; red[4 + (tid >> 6)] = s_pos; }
    __syncthreads();
    if (tid == 0) unsafeAtomicAdd(&ws->sum_all[blockIdx.x & 7], red[0] + red[1] + red[2] + red[3]);
    if (tid == 1) unsafeAtomicAdd(&ws->sum_pos[blockIdx.x & 7], red[4] + red[5] + red[6] + red[7]);
}

// ---------------------------------------------------------------- direct loss
// 4 rows per wave: 16-lane group per row, float4 per lane.
__global__ __launch_bounds__(256) void direct_kernel(const float* __restrict__ logits,
                                                     const int* __restrict__ labels,
                                                     Accum* __restrict__ ws) {
    __shared__ int   ltc[NCLS];
    __shared__ float wsum[4];
    if (threadIdx.x < NCLS) ltc[threadIdx.x] = 0;
    __syncthreads();

    const int wid  = threadIdx.x >> 6;
    const int lane = threadIdx.x & 63;
    const int sub  = lane >> 4;
    const int grpb = lane & ~15;

    float lsum = 0.0f;
    for (int q = blockIdx.x * 4 + wid; q < NQUAD; q += gridDim.x * 4) {
        const float4 x = reinterpret_cast<const float4*>(logits)[q * 64 + lane];
        const int lab  = labels[SUPPORT + q * 4 + sub];
        float m = fmaxf(fmaxf(x.x, x.y), fmaxf(x.z, x.w));
        #pragma unroll
        for (int off = 1; off < 16; off <<= 1) m = fmaxf(m, __shfl_xor(m, off));
        float e = __expf(x.x - m) + __expf(x.y - m) + __expf(x.z - m) + __expf(x.w - m);
        #pragma unroll
        for (int off = 1; off < 16; off <<= 1) e += __shfl_xor(e, off);
        const int l3 = lab & 3;
        const float sel = l3 == 0 ? x.x : l3 == 1 ? x.y : l3 == 2 ? x.z : x.w;
        const float xl = __shfl(sel, grpb + (lab >> 2));
        if ((lane & 15) == 0) {
            lsum += m + __logf(e) - xl;
            atomicAdd(&ltc[lab], 1);
        }
    }
    #pragma unroll
    for (int off = 1; off < 64; off <<= 1) lsum += __shfl_xor(lsum, off);
    if (lane == 0) wsum[wid] = lsum;
    __syncthreads();
    if (threadIdx.x == 0)
        unsafeAtomicAdd(&ws->nll_sum[blockIdx.x & 7], wsum[0] + wsum[1] + wsum[2] + wsum[3]);
    if (threadIdx.x < NCLS) {
        int v = ltc[threadIdx.x];
        if (v) atomicAdd(&ws->tgt_cnt[threadIdx.x], v);
    }
}

// ---------------------------------------------------------------- finalize
__global__ void final_kernel(const Accum* __restrict__ ws, float* __restrict__ out) {
    if (threadIdx.x == 0 && blockIdx.x == 0) {
        long long pos = 0;
        for (int c = 0; c < NCLS; ++c)
            pos += (long long)ws->sup_cnt[c] * (long long)ws->tgt_cnt[c];
        const long long tot = (long long)TARGET * SUPPORT;
        double S = 0.0, P = 0.0;
        for (int i = 0; i < 8; ++i) { S += ws->sum_all[i]; P += ws->sum_pos[i]; }
        out[0] = (float)((S - P) / ((double)pos * (double)(tot - pos)));
        float nll = 0.0f;
        for (int i = 0; i < 8; ++i) nll += ws->nll_sum[i];
        out[1] = nll / (float)TARGET;
    }
}

// ---------------------------------------------------------------- launch
extern "C" void kernel_launch(void* const* d_in, const int* in_sizes, int n_in,
                              void* d_out, int out_size, void* d_ws, size_t ws_size,
                              hipStream_t stream) {
    const float* logits = (const float*)d_in[0];   // (65024, 64) f32
    const float* ip     = (const float*)d_in[1];   // (65024, 512) f32
    const int*   labels = (const int*)d_in[2];     // (65536,) int
    float* out = (float*)d_out;
    Accum* ws  = (Accum*)d_ws;

    hipMemsetAsync(ws, 0, sizeof(Accum), stream);
    prep_kernel<<<1, 512, 0, stream>>>(labels, ws);
    pos_hist_kernel<<<TARGET * 8 / 256, 256, 0, stream>>>(ip, labels, ws);
    cdf_kernel<<<1, 128, 0, stream>>>(ws);
    direct_kernel<<<2048, 256, 0, stream>>>(logits, labels, ws);
    gather_sum_kernel<<<2048, 256, 0, stream>>>(ip, labels, ws);
    final_kernel<<<1, 64, 0, stream>>>(ws, out);
}

// Round 5
// 119.204 us; speedup vs baseline: 1.2594x; 1.2594x over previous
//
#include <hip/hip_runtime.h>

#define TSIZE   151
#define SUPPORT 512
#define TARGET  65024
#define NCLS    64
#define NPAIR   (TARGET / 2)   // 32512 row-pairs
#define NQUAD   (TARGET / 4)   // 16256 row-quads for direct part
#define GS_BLK  (NPAIR / 16)   // 2032 gather blocks, 16 row-pairs each
#define PH_BLK  2032           // pos_hist blocks (8 threads/row)
#define DR_BLK  1024           // direct blocks

struct Accum {
    float hist_pos_sp[8][80];
    float A[80];                // C[idx+1]
    float B[80];                // Hpos[idx+1]
    float sum_all[8];
    float sum_pos[8];
    float nll_sum[8];
    int   sup_cnt[NCLS];
    int   tgt_cnt[NCLS];
    int   cls_off[NCLS + 1];
    int   cls_col[SUPPORT];
    unsigned long long mask[NCLS * 8];
};

__device__ __forceinline__ void lds_fadd(float* p, float v) {
    __hip_atomic_fetch_add(p, v, __ATOMIC_RELAXED, __HIP_MEMORY_SCOPE_WORKGROUP);
}

// ---------------------------------------------------------------- prep
__global__ void prep_kernel(const int* __restrict__ labels, Accum* ws) {
    __shared__ int sh_cnt[NCLS], sh_off[NCLS], cur[NCLS];
    const int t = threadIdx.x;
    if (t < NCLS) { sh_cnt[t] = 0; cur[t] = 0; }
    __syncthreads();
    const int c = labels[t];
    atomicAdd(&sh_cnt[c], 1);
    atomicOr(&ws->mask[c * 8 + (t >> 6)], 1ull << (t & 63));
    __syncthreads();
    if (t == 0) {
        int o = 0;
        for (int i = 0; i < NCLS; ++i) { sh_off[i] = o; ws->cls_off[i] = o; o += sh_cnt[i]; }
        ws->cls_off[NCLS] = o;
    }
    __syncthreads();
    if (t < NCLS) ws->sup_cnt[t] = sh_cnt[t];
    const int slot = atomicAdd(&cur[c], 1);
    ws->cls_col[sh_off[c] + slot] = t;
}

// ---------------------------------------------------------------- pos_hist + direct (fused dispatch)
__global__ __launch_bounds__(256) void phdir_kernel(const float* __restrict__ ip,
                                                    const float* __restrict__ logits,
                                                    const int* __restrict__ labels,
                                                    Accum* __restrict__ ws) {
    const int tid = threadIdx.x;
    if (blockIdx.x < PH_BLK) {
        // ---- pos histogram: 8 threads per target row gather positive columns
        __shared__ float hp[77][8];
        __shared__ int   colL[SUPPORT];
        __shared__ int   offL[NCLS + 1];
        for (int i = tid; i < 77 * 8; i += 256) (&hp[0][0])[i] = 0.0f;
        for (int i = tid; i < SUPPORT; i += 256) colL[i] = ws->cls_col[i];
        if (tid <= NCLS) offL[tid] = ws->cls_off[tid];
        __syncthreads();

        const int row = (blockIdx.x * 256 + tid) >> 3;
        const int sl  = tid & 7;
        {
            const int c    = labels[SUPPORT + row];
            const int base = offL[c];
            const int cnt  = offL[c + 1] - base;
            const float* rptr = ip + (size_t)row * SUPPORT;
            for (int j = sl; j < cnt; j += 8) {
                const float s  = rptr[colL[base + j]];
                const float u  = s * 75.0f;
                const float fl = floorf(u);
                const float fr = u - fl;
                int idx = (int)fl;
                idx = idx < 0 ? 0 : (idx > 74 ? 74 : idx);
                lds_fadd(&hp[idx][sl],     fr);
                lds_fadd(&hp[idx + 1][sl], 1.0f - fr);
            }
        }
        __syncthreads();
        if (tid < 76) {
            float s = 0.0f;
            #pragma unroll
            for (int r = 0; r < 8; ++r) s += hp[tid][r];
            if (s != 0.0f) unsafeAtomicAdd(&ws->hist_pos_sp[blockIdx.x & 7][tid], s);
        }
    } else {
        // ---- direct loss: 4 rows per wave, 16-lane group per row
        __shared__ int   ltc[NCLS];
        __shared__ float wsum[4];
        if (tid < NCLS) ltc[tid] = 0;
        __syncthreads();

        const int bid  = blockIdx.x - PH_BLK;
        const int wid  = tid >> 6;
        const int lane = tid & 63;
        const int sub  = lane >> 4;
        const int grpb = lane & ~15;

        float lsum = 0.0f;
        for (int q = bid * 4 + wid; q < NQUAD; q += DR_BLK * 4) {
            const float4 x = reinterpret_cast<const float4*>(logits)[q * 64 + lane];
            const int lab  = labels[SUPPORT + q * 4 + sub];
            float m = fmaxf(fmaxf(x.x, x.y), fmaxf(x.z, x.w));
            #pragma unroll
            for (int off = 1; off < 16; off <<= 1) m = fmaxf(m, __shfl_xor(m, off));
            float e = __expf(x.x - m) + __expf(x.y - m) + __expf(x.z - m) + __expf(x.w - m);
            #pragma unroll
            for (int off = 1; off < 16; off <<= 1) e += __shfl_xor(e, off);
            const int l3 = lab & 3;
            const float sel = l3 == 0 ? x.x : l3 == 1 ? x.y : l3 == 2 ? x.z : x.w;
            const float xl = __shfl(sel, grpb + (lab >> 2));
            if ((lane & 15) == 0) {
                lsum += m + __logf(e) - xl;
                atomicAdd(&ltc[lab], 1);
            }
        }
        #pragma unroll
        for (int off = 1; off < 64; off <<= 1) lsum += __shfl_xor(lsum, off);
        if (lane == 0) wsum[wid] = lsum;
        __syncthreads();
        if (tid == 0)
            unsafeAtomicAdd(&ws->nll_sum[bid & 7], wsum[0] + wsum[1] + wsum[2] + wsum[3]);
        if (tid < NCLS) {
            int v = ltc[tid];
            if (v) atomicAdd(&ws->tgt_cnt[tid], v);
        }
    }
}

// ---------------------------------------------------------------- cdf build
__global__ void cdf_kernel(Accum* ws) {
    __shared__ float H[80];
    const int t = threadIdx.x;
    if (t < 76) {
        float s = 0.0f;
        #pragma unroll
        for (int r = 0; r < 8; ++r) s += ws->hist_pos_sp[r][t];
        H[t] = s;
    }
    if (t >= 76 && t < 80) H[t] = 0.0f;
    __syncthreads();
    if (t == 0) {
        float c = 0.0f;
        float C[77];
        for (int i = 0; i < 76; ++i) { c += H[i]; C[i] = c; }
        for (int idx = 0; idx < 75; ++idx) { ws->A[idx] = C[idx + 1]; ws->B[idx] = H[idx + 1]; }
        ws->A[75] = C[75]; ws->B[75] = 0.0f;
        for (int i = 76; i < 80; ++i) { ws->A[i] = 0.0f; ws->B[i] = 0.0f; }
    }
}

// ---------------------------------------------------------------- main pass
// Block owns 16 contiguous row-pairs (64 KB). Fully unrolled 4 groups x 4
// float4 loads with next-group prefetch -> 4-8 independent loads in flight.
// All mask/label state pre-staged in LDS; zero dependent global chains.
__global__ __launch_bounds__(256) void gather_sum_kernel(const float* __restrict__ ip,
                                                         const int* __restrict__ labels,
                                                         Accum* __restrict__ ws) {
    __shared__ float2 tab[76 * 16];                 // 16-way replicated, idx-staggered
    __shared__ unsigned long long rowmask[32][8];   // per-row 512-bit mask words
    __shared__ float red[8];
    const int tid = threadIdx.x;
    const int c   = tid & 15;

    for (int i = tid; i < 76 * 16; i += 256) {
        const int idx = i >> 4, cc = i & 15;
        tab[(idx << 4) + ((cc + idx) & 15)] = make_float2(ws->A[idx], ws->B[idx]);
    }
    {
        const int r = tid >> 3, w = tid & 7;
        const int lab = labels[SUPPORT + blockIdx.x * 32 + r];
        rowmask[r][w] = ws->mask[lab * 8 + w];
    }
    __syncthreads();

    const int half = tid >> 7;
    const int word = (tid & 127) >> 4;
    const int bit0 = (tid << 2) & 63;
    const float4* ip4 = reinterpret_cast<const float4*>(ip)
                      + (size_t)blockIdx.x * 16 * 256 + tid;

    float s_all = 0.0f, s_pos = 0.0f;
    float4 v[4], vn[4];
    #pragma unroll
    for (int j = 0; j < 4; ++j) v[j] = ip4[j * 256];

    #pragma unroll
    for (int g = 0; g < 4; ++g) {
        if (g < 3) {
            #pragma unroll
            for (int j = 0; j < 4; ++j) vn[j] = ip4[((g + 1) * 4 + j) * 256];
        }
        #pragma unroll
        for (int j = 0; j < 4; ++j) {
            const int lr = ((g * 4 + j) << 1) + half;
            const unsigned long long mw = rowmask[lr][word];
            const unsigned nib = (unsigned)(mw >> bit0) & 0xFu;
            #pragma unroll
            for (int e = 0; e < 4; ++e) {
                const float s  = e == 0 ? v[j].x : e == 1 ? v[j].y : e == 2 ? v[j].z : v[j].w;
                const float u  = s * 75.0f;
                const float fl = floorf(u);
                const float fr = u - fl;
                int idx = (int)fl;
                idx = idx < 0 ? 0 : (idx > 74 ? 74 : idx);
                const float2 ab = tab[(idx << 4) + ((c + idx) & 15)];
                const float gg = fmaf(-fr, ab.y, ab.x);   // C[idx+1] - fr*H[idx+1]
                s_all += gg;
                if (nib & (1u << e)) s_pos += gg;
            }
        }
        if (g < 3) {
            #pragma unroll
            for (int j = 0; j < 4; ++j) v[j] = vn[j];
        }
    }

    #pragma unroll
    for (int off = 1; off < 64; off <<= 1) {
        s_all += __shfl_xor(s_all, off);
        s_pos += __shfl_xor(s_pos, off);
    }
    if ((tid & 63) == 0) { red[tid >> 6] = s_all; red[4 + (tid >> 6)] = s_pos; }
    __syncthreads();
    if (tid == 0) unsafeAtomicAdd(&ws->sum_all[blockIdx.x & 7], red[0] + red[1] + red[2] + red[3]);
    if (tid == 1) unsafeAtomicAdd(&ws->sum_pos[blockIdx.x & 7], red[4] + red[5] + red[6] + red[7]);
}

// ---------------------------------------------------------------- finalize
__global__ void final_kernel(const Accum* __restrict__ ws, float* __restrict__ out) {
    if (threadIdx.x == 0 && blockIdx.x == 0) {
        long long pos = 0;
        for (int c = 0; c < NCLS; ++c)
            pos += (long long)ws->sup_cnt[c] * (long long)ws->tgt_cnt[c];
        const long long tot = (long long)TARGET * SUPPORT;
        double S = 0.0, P = 0.0;
        for (int i = 0; i < 8; ++i) { S += ws->sum_all[i]; P += ws->sum_pos[i]; }
        out[0] = (float)((S - P) / ((double)pos * (double)(tot - pos)));
        float nll = 0.0f;
        for (int i = 0; i < 8; ++i) nll += ws->nll_sum[i];
        out[1] = nll / (float)TARGET;
    }
}

// ---------------------------------------------------------------- launch
extern "C" void kernel_launch(void* const* d_in, const int* in_sizes, int n_in,
                              void* d_out, int out_size, void* d_ws, size_t ws_size,
                              hipStream_t stream) {
    const float* logits = (const float*)d_in[0];   // (65024, 64) f32
    const float* ip     = (const float*)d_in[1];   // (65024, 512) f32
    const int*   labels = (const int*)d_in[2];     // (65536,) int
    float* out = (float*)d_out;
    Accum* ws  = (Accum*)d_ws;

    hipMemsetAsync(ws, 0, sizeof(Accum), stream);
    prep_kernel<<<1, 512, 0, stream>>>(labels, ws);
    phdir_kernel<<<PH_BLK + DR_BLK, 256, 0, stream>>>(ip, logits, labels, ws);
    cdf_kernel<<<1, 128, 0, stream>>>(ws);
    gather_sum_kernel<<<GS_BLK, 256, 0, stream>>>(ip, labels, ws);
    final_kernel<<<1, 64, 0, stream>>>(ws, out);
}

// Round 6
// 88.127 us; speedup vs baseline: 1.7035x; 1.3526x over previous
//
#include <hip/hip_runtime.h>

#define TSIZE   151
#define SUPPORT 512
#define TARGET  65024
#define NCLS    64
#define NQUAD   (TARGET / 4)   // 16256 row-quads for direct part
#define GS_BLK  (TARGET / 64)  // 1016 gather blocks, 64 rows each
#define PH_BLK  2032           // pos_hist blocks (8 threads/row)
#define DR_BLK  1024           // direct blocks

struct Accum {
    float hist_pos_sp[8][80];
    float sum_all[8];
    float sum_pos[8];
    float nll_sum[8];
    int   sup_cnt[NCLS];
    int   tgt_cnt[NCLS];
    int   cls_off[NCLS + 1];
    int   cls_col[SUPPORT];
    unsigned long long mask[NCLS * 8];
};

__device__ __forceinline__ void lds_fadd(float* p, float v) {
    __hip_atomic_fetch_add(p, v, __ATOMIC_RELAXED, __HIP_MEMORY_SCOPE_WORKGROUP);
}

// ---------------------------------------------------------------- prep
__global__ void prep_kernel(const int* __restrict__ labels, Accum* ws) {
    __shared__ int sh_cnt[NCLS], sh_off[NCLS], cur[NCLS];
    const int t = threadIdx.x;
    if (t < NCLS) { sh_cnt[t] = 0; cur[t] = 0; }
    __syncthreads();
    const int c = labels[t];
    atomicAdd(&sh_cnt[c], 1);
    atomicOr(&ws->mask[c * 8 + (t >> 6)], 1ull << (t & 63));
    __syncthreads();
    if (t == 0) {
        int o = 0;
        for (int i = 0; i < NCLS; ++i) { sh_off[i] = o; ws->cls_off[i] = o; o += sh_cnt[i]; }
        ws->cls_off[NCLS] = o;
    }
    __syncthreads();
    if (t < NCLS) ws->sup_cnt[t] = sh_cnt[t];
    const int slot = atomicAdd(&cur[c], 1);
    ws->cls_col[sh_off[c] + slot] = t;
}

// ---------------------------------------------------------------- pos_hist + direct (fused dispatch)
__global__ __launch_bounds__(256) void phdir_kernel(const float* __restrict__ ip,
                                                    const float* __restrict__ logits,
                                                    const int* __restrict__ labels,
                                                    Accum* __restrict__ ws) {
    const int tid = threadIdx.x;
    if (blockIdx.x < PH_BLK) {
        // ---- pos histogram: 8 threads per target row gather positive columns
        __shared__ float hp[77][8];
        __shared__ int   colL[SUPPORT];
        __shared__ int   offL[NCLS + 1];
        for (int i = tid; i < 77 * 8; i += 256) (&hp[0][0])[i] = 0.0f;
        for (int i = tid; i < SUPPORT; i += 256) colL[i] = ws->cls_col[i];
        if (tid <= NCLS) offL[tid] = ws->cls_off[tid];
        __syncthreads();

        const int row = (blockIdx.x * 256 + tid) >> 3;
        const int sl  = tid & 7;
        {
            const int c    = labels[SUPPORT + row];
            const int base = offL[c];
            const int cnt  = offL[c + 1] - base;
            const float* rptr = ip + (size_t)row * SUPPORT;
            for (int j = sl; j < cnt; j += 8) {
                const float s  = rptr[colL[base + j]];
                const float u  = s * 75.0f;
                const float fl = floorf(u);
                const float fr = u - fl;
                int idx = (int)fl;
                idx = idx < 0 ? 0 : (idx > 74 ? 74 : idx);
                lds_fadd(&hp[idx][sl],     fr);
                lds_fadd(&hp[idx + 1][sl], 1.0f - fr);
            }
        }
        __syncthreads();
        if (tid < 76) {
            float s = 0.0f;
            #pragma unroll
            for (int r = 0; r < 8; ++r) s += hp[tid][r];
            if (s != 0.0f) unsafeAtomicAdd(&ws->hist_pos_sp[blockIdx.x & 7][tid], s);
        }
    } else {
        // ---- direct loss: 4 rows per wave, 16-lane group per row
        __shared__ int   ltc[NCLS];
        __shared__ float wsum[4];
        if (tid < NCLS) ltc[tid] = 0;
        __syncthreads();

        const int bid  = blockIdx.x - PH_BLK;
        const int wid  = tid >> 6;
        const int lane = tid & 63;
        const int sub  = lane >> 4;
        const int grpb = lane & ~15;

        float lsum = 0.0f;
        for (int q = bid * 4 + wid; q < NQUAD; q += DR_BLK * 4) {
            const float4 x = reinterpret_cast<const float4*>(logits)[q * 64 + lane];
            const int lab  = labels[SUPPORT + q * 4 + sub];
            float m = fmaxf(fmaxf(x.x, x.y), fmaxf(x.z, x.w));
            #pragma unroll
            for (int off = 1; off < 16; off <<= 1) m = fmaxf(m, __shfl_xor(m, off));
            float e = __expf(x.x - m) + __expf(x.y - m) + __expf(x.z - m) + __expf(x.w - m);
            #pragma unroll
            for (int off = 1; off < 16; off <<= 1) e += __shfl_xor(e, off);
            const int l3 = lab & 3;
            const float sel = l3 == 0 ? x.x : l3 == 1 ? x.y : l3 == 2 ? x.z : x.w;
            const float xl = __shfl(sel, grpb + (lab >> 2));
            if ((lane & 15) == 0) {
                lsum += m + __logf(e) - xl;
                atomicAdd(&ltc[lab], 1);
            }
        }
        #pragma unroll
        for (int off = 1; off < 64; off <<= 1) lsum += __shfl_xor(lsum, off);
        if (lane == 0) wsum[wid] = lsum;
        __syncthreads();
        if (tid == 0)
            unsafeAtomicAdd(&ws->nll_sum[bid & 7], wsum[0] + wsum[1] + wsum[2] + wsum[3]);
        if (tid < NCLS) {
            int v = ltc[tid];
            if (v) atomicAdd(&ws->tgt_cnt[tid], v);
        }
    }
}

// ---------------------------------------------------------------- main pass
// Block owns 64 contiguous rows (32 steps x 256 float4). Two named 8-deep
// float4 register sets (A/B), fully unrolled straight-line: 8-16 independent
// 16B loads in flight per wave. Per-element: 1 staggered ds_read_b64 + FMA.
// Block prologue rebuilds CDF lookup from the global pos-histogram.
__global__ __launch_bounds__(256, 3) void gather_sum_kernel(const float* __restrict__ ip,
                                                            const int* __restrict__ labels,
                                                            Accum* __restrict__ ws) {
    __shared__ float2 tab[76 * 16];                 // 16-way replicated, idx-staggered
    __shared__ unsigned long long rowmask[64][8];
    __shared__ float Hs[80];
    __shared__ float Cs[80];
    __shared__ float red[8];
    const int tid = threadIdx.x;
    const int c16 = tid & 15;

    if (tid < 76) {
        float s = 0.0f;
        #pragma unroll
        for (int r = 0; r < 8; ++r) s += ws->hist_pos_sp[r][tid];
        Hs[tid] = s;
    }
    if (tid >= 76 && tid < 80) Hs[tid] = 0.0f;
    {
        const int r  = tid >> 2;                     // 0..63
        const int w0 = (tid & 3) * 2;
        const int lab = labels[SUPPORT + blockIdx.x * 64 + r];
        const unsigned long long* mrow = ws->mask + lab * 8;
        rowmask[r][w0]     = mrow[w0];
        rowmask[r][w0 + 1] = mrow[w0 + 1];
    }
    __syncthreads();
    if (tid == 0) {
        float cacc = 0.0f;
        for (int i = 0; i < 76; ++i) { cacc += Hs[i]; Cs[i] = cacc; }
        Cs[76] = cacc;
    }
    __syncthreads();
    for (int i = tid; i < 76 * 16; i += 256) {
        const int idx = i >> 4, cc = i & 15;
        const float a = (idx < 75) ? Cs[idx + 1] : Cs[75];
        const float b = (idx < 75) ? Hs[idx + 1] : 0.0f;
        tab[(idx << 4) + ((cc + idx) & 15)] = make_float2(a, b);
    }
    __syncthreads();

    const int half = tid >> 7;
    const int word = (tid & 127) >> 4;
    const int bit0 = (tid << 2) & 63;
    const float4* base = reinterpret_cast<const float4*>(ip)
                       + (size_t)blockIdx.x * (64 * 128) + tid;

    float s_all = 0.0f, s_pos = 0.0f;
    float4 qa0, qa1, qa2, qa3, qa4, qa5, qa6, qa7;
    float4 qb0, qb1, qb2, qb3, qb4, qb5, qb6, qb7;

#define LDA(T) { qa0 = base[((T)+0)*256]; qa1 = base[((T)+1)*256]; \
                 qa2 = base[((T)+2)*256]; qa3 = base[((T)+3)*256]; \
                 qa4 = base[((T)+4)*256]; qa5 = base[((T)+5)*256]; \
                 qa6 = base[((T)+6)*256]; qa7 = base[((T)+7)*256]; }
#define LDB(T) { qb0 = base[((T)+0)*256]; qb1 = base[((T)+1)*256]; \
                 qb2 = base[((T)+2)*256]; qb3 = base[((T)+3)*256]; \
                 qb4 = base[((T)+4)*256]; qb5 = base[((T)+5)*256]; \
                 qb6 = base[((T)+6)*256]; qb7 = base[((T)+7)*256]; }
#define PE(S, E) { const float u = (S) * 75.0f; const float fl = floorf(u);          \
                   const float fr = u - fl; int idx = (int)fl;                       \
                   idx = idx < 0 ? 0 : (idx > 74 ? 74 : idx);                        \
                   const float2 ab = tab[(idx << 4) + ((c16 + idx) & 15)];           \
                   const float gg = fmaf(-fr, ab.y, ab.x);                           \
                   s_all += gg; if (nib & (1u << (E))) s_pos += gg; }
#define P1(Q, T) { const int lr = ((T) << 1) + half;                                 \
                   const unsigned long long mw = rowmask[lr][word];                  \
                   const unsigned nib = (unsigned)(mw >> bit0) & 0xFu;               \
                   PE(Q.x, 0) PE(Q.y, 1) PE(Q.z, 2) PE(Q.w, 3) }
#define PA(T) { P1(qa0,(T)+0) P1(qa1,(T)+1) P1(qa2,(T)+2) P1(qa3,(T)+3) \
                P1(qa4,(T)+4) P1(qa5,(T)+5) P1(qa6,(T)+6) P1(qa7,(T)+7) }
#define PB(T) { P1(qb0,(T)+0) P1(qb1,(T)+1) P1(qb2,(T)+2) P1(qb3,(T)+3) \
                P1(qb4,(T)+4) P1(qb5,(T)+5) P1(qb6,(T)+6) P1(qb7,(T)+7) }

    LDA(0);
    LDB(8);
    PA(0);  LDA(16);
    PB(8);  LDB(24);
    PA(16);
    PB(24);

#undef LDA
#undef LDB
#undef PE
#undef P1
#undef PA
#undef PB

    #pragma unroll
    for (int off = 1; off < 64; off <<= 1) {
        s_all += __shfl_xor(s_all, off);
        s_pos += __shfl_xor(s_pos, off);
    }
    if ((tid & 63) == 0) { red[tid >> 6] = s_all; red[4 + (tid >> 6)] = s_pos; }
    __syncthreads();
    if (tid == 0) unsafeAtomicAdd(&ws->sum_all[blockIdx.x & 7], red[0] + red[1] + red[2] + red[3]);
    if (tid == 1) unsafeAtomicAdd(&ws->sum_pos[blockIdx.x & 7], red[4] + red[5] + red[6] + red[7]);
}

// ---------------------------------------------------------------- finalize
__global__ void final_kernel(const Accum* __restrict__ ws, float* __restrict__ out) {
    if (threadIdx.x == 0 && blockIdx.x == 0) {
        long long pos = 0;
        for (int c = 0; c < NCLS; ++c)
            pos += (long long)ws->sup_cnt[c] * (long long)ws->tgt_cnt[c];
        const long long tot = (long long)TARGET * SUPPORT;
        double S = 0.0, P = 0.0;
        for (int i = 0; i < 8; ++i) { S += ws->sum_all[i]; P += ws->sum_pos[i]; }
        out[0] = (float)((S - P) / ((double)pos * (double)(tot - pos)));
        float nll = 0.0f;
        for (int i = 0; i < 8; ++i) nll += ws->nll_sum[i];
        out[1] = nll / (float)TARGET;
    }
}

// ---------------------------------------------------------------- launch
extern "C" void kernel_launch(void* const* d_in, const int* in_sizes, int n_in,
                              void* d_out, int out_size, void* d_ws, size_t ws_size,
                              hipStream_t stream) {
    const float* logits = (const float*)d_in[0];   // (65024, 64) f32
    const float* ip     = (const float*)d_in[1];   // (65024, 512) f32
    const int*   labels = (const int*)d_in[2];     // (65536,) int
    float* out = (float*)d_out;
    Accum* ws  = (Accum*)d_ws;

    hipMemsetAsync(ws, 0, sizeof(Accum), stream);
    prep_kernel<<<1, 512, 0, stream>>>(labels, ws);
    phdir_kernel<<<PH_BLK + DR_BLK, 256, 0, stream>>>(ip, logits, labels, ws);
    gather_sum_kernel<<<GS_BLK, 256, 0, stream>>>(ip, labels, ws);
    final_kernel<<<1, 64, 0, stream>>>(ws, out);
}